// Round 10
// baseline (114.716 us; speedup 1.0000x reference)
//
#include <hip/hip_runtime.h>
#include <hip/hip_bf16.h>
#include <math.h>

// Problem constants (reference: B=32, P=256, D=64, T=4096, SCALE=1)
#define Bb 32
#define Pp 256
#define Dd 64
#define Tt 4096

typedef unsigned short ushort_t;
typedef __attribute__((ext_vector_type(8))) short bf16x8;   // 8 bf16 = 4 VGPRs
typedef __attribute__((ext_vector_type(4))) float f32x4;

// Partials: 64 per (b,p), packed float2(lm = M + log2(ss), u = vv/ss).
#define TRIP_BYTES ((size_t)Bb * Pp * 64 * 8)    // 4,194,304
#define WS_NEED    TRIP_BYTES

// Log2-domain logits (R14/R16-validated): one v_exp_f32 per exp.
#define C2 (-0.7213475204444817f)   // -0.5 * log2(e)

__device__ __forceinline__ float fexp2(float x) {
  float r; asm("v_exp_f32 %0, %1" : "=v"(r) : "v"(x)); return r;
}
__device__ __forceinline__ float flog2(float x) {
  float r; asm("v_log_f32 %0, %1" : "=v"(r) : "v"(x)); return r;
}
__device__ __forceinline__ float frcp(float x) {
  float r; asm("v_rcp_f32 %0, %1" : "=v"(r) : "v"(x)); return r;
}

// ---- DPP row-local shuffle on the VALU pipe (R13-proven ctrl codes).
// quad_perm xor1 = 0xB1, quad_perm xor2 = 0x4E,
// row_half_mirror = 0x141 (cross-4 merge), row_mirror = 0x140 (cross-8).
template <int CTRL>
__device__ __forceinline__ float dppf(float x) {
  return __builtin_bit_cast(float,
      __builtin_amdgcn_update_dpp(0, __builtin_bit_cast(int, x), CTRL, 0xF, 0xF, true));
}

// R9-proven split-bf16 6-MFMA product (drops al*bl, ~2^-17 rel err)
__device__ __forceinline__ f32x4 mfma6(bf16x8 ah0, bf16x8 ah1, bf16x8 al0, bf16x8 al1,
                                       bf16x8 bh0, bf16x8 bh1, bf16x8 bl0, bf16x8 bl1) {
  f32x4 a = (f32x4)0.f;
  a = __builtin_amdgcn_mfma_f32_16x16x32_bf16(ah0, bh0, a, 0, 0, 0);
  a = __builtin_amdgcn_mfma_f32_16x16x32_bf16(ah1, bh1, a, 0, 0, 0);
  a = __builtin_amdgcn_mfma_f32_16x16x32_bf16(ah0, bl0, a, 0, 0, 0);
  a = __builtin_amdgcn_mfma_f32_16x16x32_bf16(al0, bh0, a, 0, 0, 0);
  a = __builtin_amdgcn_mfma_f32_16x16x32_bf16(ah1, bl1, a, 0, 0, 0);
  a = __builtin_amdgcn_mfma_f32_16x16x32_bf16(al1, bh1, a, 0, 0, 0);
  return a;
}

// ---- In-register split-bf16 of 8 floats (R21-proven spill-free: straight-
// line, NAMED SCALARS, constant vector indices only). RNE hi + RNE residual.
__device__ __forceinline__ void cvt8(const float4 a, const float4 b,
                                     bf16x8& hi, bf16x8& lo) {
#define CVT1(X, IDX)                                          \
  {                                                           \
    const __hip_bfloat16 hb = __float2bfloat16(X);            \
    const float hf = __bfloat162float(hb);                    \
    const __hip_bfloat16 lb = __float2bfloat16((X) - hf);     \
    hi[IDX] = __builtin_bit_cast(short, hb);                  \
    lo[IDX] = __builtin_bit_cast(short, lb);                  \
  }
  CVT1(a.x, 0) CVT1(a.y, 1) CVT1(a.z, 2) CVT1(a.w, 3)
  CVT1(b.x, 4) CVT1(b.y, 5) CVT1(b.z, 6) CVT1(b.w, 7)
#undef CVT1
}

// ==================== Phase 1: one-pass fused prefix-softmax ================
// R22: prefix-recompute sg-split, third attempt — now structurally armed:
// R21's measured VGPR is 84, so the (256,4) 128-reg cap that spilled R14/R15
// no longer binds. Diagnosis (stable over R18-R21): all pipes <50% busy at
// 2 waves/SIMD; R19 (dual-row ILP) and R20 (software pipeline) proved the
// stalls are not intra-wave-fillable -> only TLP fills them. R16's lesson:
// never duplicate butterflies; duplicate ONLY the cheap R-spine.
//  - each (b,strip) -> TWO blocks; grid 1024 = 4 blocks/CU = 4 waves/SIMD.
//  - half0: sgs 0..SPLIT-1 full. half1: sgs 0..SPLIT-1 LIGHT (MFMA + scores
//    + 3 scan shuffles + R update only; bitwise-identical R, no cc/av, no
//    butterfly, no store), then sgs SPLIT..15 full. SPLIT=10 balances
//    (10 vs 10*0.45+6 ~ 10.5).
//  - butterfly/store totals unchanged vs R21; MFMA+scan totals x1.31.
//  - A-prefetch rotation dropped: 4-wave TLP hides L1-hot A latency, saves
//    16 live regs under the 128 cap.
// Numerics: R21-proven (in-register split-bf16, log2 domain, M-first
// exact-max softmax, float2(lm,u) partials); R bitwise-identical across
// halves (same op order).
#define SPLIT 10
__global__ __launch_bounds__(256, 4) void k_main(const float* __restrict__ data,
                                                 const float* __restrict__ targets,
                                                 const float* __restrict__ task_pool,
                                                 float2* __restrict__ trips) {
  const int tid  = threadIdx.x;
  const int wid  = tid >> 6;
  const int lane = tid & 63;
  const int quad = lane >> 4;
  const int l16  = lane & 15;
  const int b     = blockIdx.x >> 5;            // 32 blocks per b
  const int strip = (blockIdx.x >> 1) & 15;
  const int half  = blockIdx.x & 1;
  const int t0    = strip * 256;
  const int wstrip = strip * 4 + wid;           // 0..63 (this wave's t-subset id)

  // ---- B fragments for this wave's 64 t-columns: load f32 (wave-unique
  // rows), convert in-register ONCE, VGPR-resident for all sgs.
  bf16x8 vbh0[4], vbh1[4], vbl0[4], vbl1[4];
#pragma unroll
  for (int nt = 0; nt < 4; ++nt) {
    const float* wr = task_pool + (size_t)(t0 + wid * 64 + nt * 16 + l16) * Dd + quad * 8;
    cvt8(*(const float4*)(wr),      *(const float4*)(wr + 4),  vbh0[nt], vbl0[nt]);
    cvt8(*(const float4*)(wr + 32), *(const float4*)(wr + 36), vbh1[nt], vbl1[nt]);
  }

  const float* arow = data + (size_t)b * Pp * Dd;
  const float* tgt  = targets + b * Pp;
  float2* __restrict__ trb = trips + (size_t)b * Pp * 64;

  float R[4];                                   // per-column running prefix (log2)
#pragma unroll
  for (int nt = 0; nt < 4; ++nt) R[nt] = 0.f;

  // ---- LIGHT pass (half1 only): recompute prefix R for sgs 0..SPLIT-1.
  // Identical op order to the full pass's R update -> bitwise-identical R.
  if (half) {
#pragma unroll 1
    for (int sg = 0; sg < SPLIT; ++sg) {
      const float* ar = arow + (size_t)(sg * 16 + l16) * Dd + quad * 8;
      bf16x8 ah0, ah1, al0, al1;
      cvt8(*(const float4*)(ar),      *(const float4*)(ar + 4),  ah0, al0);
      cvt8(*(const float4*)(ar + 32), *(const float4*)(ar + 36), ah1, al1);
      const float4 tq = *(const float4*)(tgt + sg * 16 + quad * 4);
#pragma unroll
      for (int nt = 0; nt < 4; ++nt) {
        const f32x4 a = mfma6(ah0, ah1, al0, al1,
                              vbh0[nt], vbh1[nt], vbl0[nt], vbl1[nt]);
        float sc0, sc1, sc2, sc3;
        { const float e = tq.x - a[0]; sc0 = C2 * e * e; }
        { const float e = tq.y - a[1]; sc1 = C2 * e * e; }
        { const float e = tq.z - a[2]; sc2 = C2 * e * e; }
        { const float e = tq.w - a[3]; sc3 = C2 * e * e; }
        const float colsum = (sc0 + sc1) + (sc2 + sc3);
        const float x1 = __shfl_xor(colsum, 16, 64);
        const float x2 = __shfl_xor(colsum, 32, 64);
        const float x3 = __shfl_xor(x1, 32, 64);
        R[nt] += ((colsum + x1) + (x2 + x3));
      }
    }
  }

  // ---- FULL pass: half0 does sgs [0,SPLIT), half1 does [SPLIT,16).
  const int fullBeg = half ? SPLIT : 0;
  const int fullEnd = half ? 16 : SPLIT;
#pragma unroll 1
  for (int sg = fullBeg; sg < fullEnd; ++sg) {
    const float* ar = arow + (size_t)(sg * 16 + l16) * Dd + quad * 8;
    bf16x8 ah0, ah1, al0, al1;
    cvt8(*(const float4*)(ar),      *(const float4*)(ar + 4),  ah0, al0);
    cvt8(*(const float4*)(ar + 32), *(const float4*)(ar + 36), ah1, al1);
    const float4 tq = *(const float4*)(tgt + sg * 16 + quad * 4);

    float cc[4][4], av[4][4];
#pragma unroll
    for (int nt = 0; nt < 4; ++nt) {
      const f32x4 a = mfma6(ah0, ah1, al0, al1,
                            vbh0[nt], vbh1[nt], vbl0[nt], vbl1[nt]);
      float sc0, sc1, sc2, sc3;
      { const float e = tq.x - a[0]; sc0 = C2 * e * e; }
      { const float e = tq.y - a[1]; sc1 = C2 * e * e; }
      { const float e = tq.z - a[2]; sc2 = C2 * e * e; }
      { const float e = tq.w - a[3]; sc3 = C2 * e * e; }

      // quad-exclusive prefix of column sums (R11-proven; cross-row -> DS)
      const float colsum = (sc0 + sc1) + (sc2 + sc3);
      const float x1 = __shfl_xor(colsum, 16, 64);
      const float x2 = __shfl_xor(colsum, 32, 64);
      const float x3 = __shfl_xor(x1, 32, 64);
      const float pre = (quad == 0) ? 0.f
                      : (quad == 1) ? x1
                      : (quad == 2) ? (x2 + x3)
                                    : (x1 + x2 + x3);
      const float base = R[nt] + pre;
      cc[nt][0] = base;
      cc[nt][1] = base + sc0;
      cc[nt][2] = cc[nt][1] + sc1;
      cc[nt][3] = cc[nt][2] + sc2;
      av[nt][0] = a[0]; av[nt][1] = a[1]; av[nt][2] = a[2]; av[nt][3] = a[3];
      R[nt] += ((colsum + x1) + (x2 + x3));     // inclusive through this sg
    }

    // ---- M-first softmax: exact max over 64 t (in-lane 4 + DPP butterfly)
    float M[4];
#pragma unroll
    for (int r = 0; r < 4; ++r)
      M[r] = fmaxf(fmaxf(cc[0][r], cc[1][r]), fmaxf(cc[2][r], cc[3][r]));
#pragma unroll
    for (int r = 0; r < 4; ++r) M[r] = fmaxf(M[r], dppf<0xB1>(M[r]));   // xor1
#pragma unroll
    for (int r = 0; r < 4; ++r) M[r] = fmaxf(M[r], dppf<0x4E>(M[r]));   // xor2
#pragma unroll
    for (int r = 0; r < 4; ++r) M[r] = fmaxf(M[r], dppf<0x141>(M[r]));  // cross-4
#pragma unroll
    for (int r = 0; r < 4; ++r) M[r] = fmaxf(M[r], dppf<0x140>(M[r]));  // cross-8

    // single exp2 per column against the exact max (argmax term == 1)
    float ss[4], vv[4];
#pragma unroll
    for (int r = 0; r < 4; ++r) {
      float s = 0.f, v = 0.f;
#pragma unroll
      for (int nt = 0; nt < 4; ++nt) {
        const float e = fexp2(cc[nt][r] - M[r]);
        s += e;
        v = fmaf(e, av[nt][r], v);
      }
      ss[r] = s; vv[r] = v;
    }

#pragma unroll
    for (int r = 0; r < 4; ++r) { ss[r] += dppf<0xB1>(ss[r]);  vv[r] += dppf<0xB1>(vv[r]); }
#pragma unroll
    for (int r = 0; r < 4; ++r) { ss[r] += dppf<0x4E>(ss[r]);  vv[r] += dppf<0x4E>(vv[r]); }
#pragma unroll
    for (int r = 0; r < 4; ++r) { ss[r] += dppf<0x141>(ss[r]); vv[r] += dppf<0x141>(vv[r]); }
#pragma unroll
    for (int r = 0; r < 4; ++r) { ss[r] += dppf<0x140>(ss[r]); vv[r] += dppf<0x140>(vv[r]); }

    if (l16 == 0) {
#pragma unroll
      for (int r = 0; r < 4; ++r) {
        const float lm = M[r] + flog2(ss[r]);   // ss >= 1 -> log2 safe
        const float u  = vv[r] * frcp(ss[r]);
        const int p = sg * 16 + quad * 4 + r;
        trb[p * 64 + wstrip] = make_float2(lm, u);
      }
    }
  }
}

// ==================== Phase 2: cross-strip merge (separate, parallel) =======
// R18-proven: one 64-lane wave per (b,p) row, 2048-wave parallelism. (R17's
// fused last-block merge was a 78us serial tail at 1.5% occupancy — never
// fuse this.)
__global__ __launch_bounds__(256) void k_merge(const float2* __restrict__ ws,
                                               float* __restrict__ out) {
  const int gt   = blockIdx.x * 256 + threadIdx.x;
  const int bp   = gt >> 6;
  const int lane = gt & 63;
  const float2 e = ws[(size_t)bp * 64 + lane];
  float M = e.x;
#pragma unroll
  for (int off = 32; off; off >>= 1) M = fmaxf(M, __shfl_xor(M, off, 64));
  const float f = fexp2(e.x - M);
  float S = f, V = f * e.y;
#pragma unroll
  for (int off = 32; off; off >>= 1) {
    S += __shfl_xor(S, off, 64);
    V += __shfl_xor(V, off, 64);
  }
  if (lane == 0) out[bp] = V / S;
}

// ============== Fallback (tiny ws): fused R1 structure + merge ==============
__global__ __launch_bounds__(256) void k_scan_fused(const float* __restrict__ data,
                                                    const float* __restrict__ targets,
                                                    const float* __restrict__ task_pool,
                                                    float2* __restrict__ ws) {
  const int b     = blockIdx.x >> 4;
  const int wid   = threadIdx.x >> 6;
  const int lane  = threadIdx.x & 63;
  const int chunk = ((blockIdx.x & 15) << 2) | wid;
  const int t     = (chunk << 6) | lane;
  float w[Dd];
#pragma unroll
  for (int d = 0; d < Dd; d += 4) {
    const float4 r = *(const float4*)(task_pool + (size_t)t * Dd + d);
    w[d] = r.x; w[d + 1] = r.y; w[d + 2] = r.z; w[d + 3] = r.w;
  }
  const float* drow = data + (size_t)b * (Pp * Dd);
  const float* tgt  = targets + b * Pp;
  float2* wsb       = ws + (size_t)b * (Pp * 64);
  float c = 0.f;
  for (int p = 0; p < Pp; ++p) {
    float a0 = 0.f, a1 = 0.f, a2 = 0.f, a3 = 0.f;
    const float* r = drow + p * Dd;
#pragma unroll
    for (int d = 0; d < Dd; d += 4) {
      a0 = fmaf(r[d], w[d], a0);         a1 = fmaf(r[d + 1], w[d + 1], a1);
      a2 = fmaf(r[d + 2], w[d + 2], a2); a3 = fmaf(r[d + 3], w[d + 3], a3);
    }
    const float pred = (a0 + a1) + (a2 + a3);
    float m = c;
#pragma unroll
    for (int off = 32; off; off >>= 1) m = fmaxf(m, __shfl_xor(m, off, 64));
    const float e = fexp2(c - m);
    float s = e, v = e * pred;
#pragma unroll
    for (int off = 32; off; off >>= 1) {
      s += __shfl_xor(s, off, 64);
      v += __shfl_xor(v, off, 64);
    }
    if (lane == 0) wsb[p * 64 + chunk] = make_float2(m + flog2(s), v * frcp(s));
    const float err = tgt[p] - pred;
    c = fmaf(C2 * err, err, c);
  }
}

extern "C" void kernel_launch(void* const* d_in, const int* in_sizes, int n_in,
                              void* d_out, int out_size, void* d_ws, size_t ws_size,
                              hipStream_t stream) {
  const float* data      = (const float*)d_in[0];
  const float* targets   = (const float*)d_in[1];
  const float* task_pool = (const float*)d_in[2];
  float* out = (float*)d_out;

  float2* trips = (float2*)d_ws;   // 4.2 MB
  if (ws_size >= WS_NEED) {
    k_main <<<dim3(Bb * 32), dim3(256), 0, stream>>>(data, targets, task_pool, trips);
    k_merge<<<dim3((Bb * Pp * 64) / 256), dim3(256), 0, stream>>>(trips, out);
  } else {
    k_scan_fused<<<dim3(512), dim3(256), 0, stream>>>(data, targets, task_pool, trips);
    k_merge<<<dim3((Bb * Pp * 64) / 256), dim3(256), 0, stream>>>(trips, out);
  }
}

// Round 11
// 94.684 us; speedup vs baseline: 1.2116x; 1.2116x over previous
//
#include <hip/hip_runtime.h>
#include <hip/hip_bf16.h>
#include <math.h>

// Problem constants (reference: B=32, P=256, D=64, T=4096, SCALE=1)
#define Bb 32
#define Pp 256
#define Dd 64
#define Tt 4096

typedef unsigned short ushort_t;
typedef __attribute__((ext_vector_type(8))) short bf16x8;   // 8 bf16 = 4 VGPRs
typedef __attribute__((ext_vector_type(4))) float f32x4;

// Partials: 64 per (b,p), packed float2(lm = M + log2(ss), u = vv/ss).
#define TRIP_BYTES ((size_t)Bb * Pp * 64 * 8)    // 4,194,304
#define WS_NEED    TRIP_BYTES

// Log2-domain logits (R14/R16-validated): one v_exp_f32 per exp.
#define C2 (-0.7213475204444817f)   // -0.5 * log2(e)

__device__ __forceinline__ float fexp2(float x) {
  float r; asm("v_exp_f32 %0, %1" : "=v"(r) : "v"(x)); return r;
}
__device__ __forceinline__ float flog2(float x) {
  float r; asm("v_log_f32 %0, %1" : "=v"(r) : "v"(x)); return r;
}
__device__ __forceinline__ float frcp(float x) {
  float r; asm("v_rcp_f32 %0, %1" : "=v"(r) : "v"(x)); return r;
}

// ---- DPP row-local shuffle on the VALU pipe (R13-proven ctrl codes).
// quad_perm xor1 = 0xB1, quad_perm xor2 = 0x4E,
// row_half_mirror = 0x141 (cross-4 merge), row_mirror = 0x140 (cross-8).
template <int CTRL>
__device__ __forceinline__ float dppf(float x) {
  return __builtin_bit_cast(float,
      __builtin_amdgcn_update_dpp(0, __builtin_bit_cast(int, x), CTRL, 0xF, 0xF, true));
}

// R9-proven split-bf16 6-MFMA product (drops al*bl, ~2^-17 rel err)
__device__ __forceinline__ f32x4 mfma6(bf16x8 ah0, bf16x8 ah1, bf16x8 al0, bf16x8 al1,
                                       bf16x8 bh0, bf16x8 bh1, bf16x8 bl0, bf16x8 bl1) {
  f32x4 a = (f32x4)0.f;
  a = __builtin_amdgcn_mfma_f32_16x16x32_bf16(ah0, bh0, a, 0, 0, 0);
  a = __builtin_amdgcn_mfma_f32_16x16x32_bf16(ah1, bh1, a, 0, 0, 0);
  a = __builtin_amdgcn_mfma_f32_16x16x32_bf16(ah0, bl0, a, 0, 0, 0);
  a = __builtin_amdgcn_mfma_f32_16x16x32_bf16(al0, bh0, a, 0, 0, 0);
  a = __builtin_amdgcn_mfma_f32_16x16x32_bf16(ah1, bl1, a, 0, 0, 0);
  a = __builtin_amdgcn_mfma_f32_16x16x32_bf16(al1, bh1, a, 0, 0, 0);
  return a;
}

// ---- In-register split-bf16 of 8 floats (R21-proven spill-free: straight-
// line, NAMED SCALARS, constant vector indices only). RNE hi + RNE residual.
__device__ __forceinline__ void cvt8(const float4 a, const float4 b,
                                     bf16x8& hi, bf16x8& lo) {
#define CVT1(X, IDX)                                          \
  {                                                           \
    const __hip_bfloat16 hb = __float2bfloat16(X);            \
    const float hf = __bfloat162float(hb);                    \
    const __hip_bfloat16 lb = __float2bfloat16((X) - hf);     \
    hi[IDX] = __builtin_bit_cast(short, hb);                  \
    lo[IDX] = __builtin_bit_cast(short, lb);                  \
  }
  CVT1(a.x, 0) CVT1(a.y, 1) CVT1(a.z, 2) CVT1(a.w, 3)
  CVT1(b.x, 4) CVT1(b.y, 5) CVT1(b.z, 6) CVT1(b.w, 7)
#undef CVT1
}

// ==================== Phase 1: one-pass fused prefix-softmax ================
// R23: REVERT to R21 (97.2us anchor) after R22 closed the occupancy line for
// good (third attempt: (256,4) cap -> cc/av scratch-demoted, WRITE 4->16MB,
// occupancy 31% yet k_main 63.9us; full body's live set needs >128 regs, and
// halving it (R16) loses more than TLP gains). ILP closed by R19/R20.
// One surgical change vs R21 — 2-SHUFFLE SCAN: since lane permutations
// commute with addition bitwise, x2 + x3 == xor32(colsum + x1). So
//   x1 = xor16(colsum); s01 = colsum + x1; x23 = xor32(s01);
//   pre = {0, x1, x23, x1 + x23};  R += s01 + x23.
// Verified per-lane: pre(quad0..2) and the R update are bitwise-identical to
// R21; pre(quad3) is one reassociation (~1 ulp on logits, harmless at our
// 5e-4 split-bf16 scale). Deletes 4 of 12 DS-pipe shuffles per sg AND
// shortens the scan's serial chain (the 2nd dependent ~120cyc DS op now
// consumes a locally-computed value).
__global__ __launch_bounds__(256, 2) void k_main(const float* __restrict__ data,
                                                 const float* __restrict__ targets,
                                                 const float* __restrict__ task_pool,
                                                 float2* __restrict__ trips) {
  const int tid  = threadIdx.x;
  const int wid  = tid >> 6;
  const int lane = tid & 63;
  const int quad = lane >> 4;
  const int l16  = lane & 15;
  const int b     = blockIdx.x >> 4;
  const int strip = blockIdx.x & 15;
  const int t0    = strip * 256;
  const int wstrip = strip * 4 + wid;           // 0..63 (this wave's t-subset id)

  // ---- B fragments for this wave's 64 t-columns: load f32 (wave-unique
  // rows), convert in-register ONCE, VGPR-resident for all 16 sgs.
  bf16x8 vbh0[4], vbh1[4], vbl0[4], vbl1[4];
#pragma unroll
  for (int nt = 0; nt < 4; ++nt) {
    const float* wr = task_pool + (size_t)(t0 + wid * 64 + nt * 16 + l16) * Dd + quad * 8;
    cvt8(*(const float4*)(wr),      *(const float4*)(wr + 4),  vbh0[nt], vbl0[nt]);
    cvt8(*(const float4*)(wr + 32), *(const float4*)(wr + 36), vbh1[nt], vbl1[nt]);
  }

  const float* arow = data + (size_t)b * Pp * Dd;
  const float* tgt  = targets + b * Pp;
  float2* __restrict__ trb = trips + (size_t)b * Pp * 64;

  float R[4];                                   // per-column running prefix (log2)
#pragma unroll
  for (int nt = 0; nt < 4; ++nt) R[nt] = 0.f;

  // prologue: A fragments (f32 -> split-bf16) + targets for sg=0
  bf16x8 ah0, ah1, al0, al1;
  {
    const float* ar = arow + (size_t)l16 * Dd + quad * 8;
    cvt8(*(const float4*)(ar),      *(const float4*)(ar + 4),  ah0, al0);
    cvt8(*(const float4*)(ar + 32), *(const float4*)(ar + 36), ah1, al1);
  }
  float4 tq = *(const float4*)(tgt + quad * 4);

#pragma unroll 1
  for (int sg = 0; sg < 16; ++sg) {
    // ---- prefetch next sg's A floats early (L1-hot; latency hidden under
    // this sg's compute; converted at the rotation point below)
    const int pn = ((sg + 1) & 15) * 16;
    const float* an = arow + (size_t)(pn + l16) * Dd + quad * 8;
    const float4 nf0 = *(const float4*)(an);
    const float4 nf1 = *(const float4*)(an + 4);
    const float4 nf2 = *(const float4*)(an + 32);
    const float4 nf3 = *(const float4*)(an + 36);
    const float4 ntq = *(const float4*)(tgt + pn + quad * 4);

    float cc[4][4], av[4][4];
#pragma unroll
    for (int nt = 0; nt < 4; ++nt) {
      const f32x4 a = mfma6(ah0, ah1, al0, al1,
                            vbh0[nt], vbh1[nt], vbl0[nt], vbl1[nt]);
      float sc0, sc1, sc2, sc3;
      { const float e = tq.x - a[0]; sc0 = C2 * e * e; }
      { const float e = tq.y - a[1]; sc1 = C2 * e * e; }
      { const float e = tq.z - a[2]; sc2 = C2 * e * e; }
      { const float e = tq.w - a[3]; sc3 = C2 * e * e; }

      // 2-shuffle quad-exclusive prefix (R23): x23 == x2 + x3 bitwise.
      const float colsum = (sc0 + sc1) + (sc2 + sc3);
      const float x1  = __shfl_xor(colsum, 16, 64);
      const float s01 = colsum + x1;
      const float x23 = __shfl_xor(s01, 32, 64);
      const float pre = (quad == 0) ? 0.f
                      : (quad == 1) ? x1
                      : (quad == 2) ? x23
                                    : (x1 + x23);
      const float base = R[nt] + pre;
      cc[nt][0] = base;
      cc[nt][1] = base + sc0;
      cc[nt][2] = cc[nt][1] + sc1;
      cc[nt][3] = cc[nt][2] + sc2;
      av[nt][0] = a[0]; av[nt][1] = a[1]; av[nt][2] = a[2]; av[nt][3] = a[3];
      R[nt] += (s01 + x23);                     // inclusive through this sg
    }

    // ---- M-first softmax: exact max over 64 t (in-lane 4 + DPP butterfly)
    float M[4];
#pragma unroll
    for (int r = 0; r < 4; ++r)
      M[r] = fmaxf(fmaxf(cc[0][r], cc[1][r]), fmaxf(cc[2][r], cc[3][r]));
#pragma unroll
    for (int r = 0; r < 4; ++r) M[r] = fmaxf(M[r], dppf<0xB1>(M[r]));   // xor1
#pragma unroll
    for (int r = 0; r < 4; ++r) M[r] = fmaxf(M[r], dppf<0x4E>(M[r]));   // xor2
#pragma unroll
    for (int r = 0; r < 4; ++r) M[r] = fmaxf(M[r], dppf<0x141>(M[r]));  // cross-4
#pragma unroll
    for (int r = 0; r < 4; ++r) M[r] = fmaxf(M[r], dppf<0x140>(M[r]));  // cross-8

    // single exp2 per column against the exact max (argmax term == 1)
    float ss[4], vv[4];
#pragma unroll
    for (int r = 0; r < 4; ++r) {
      float s = 0.f, v = 0.f;
#pragma unroll
      for (int nt = 0; nt < 4; ++nt) {
        const float e = fexp2(cc[nt][r] - M[r]);
        s += e;
        v = fmaf(e, av[nt][r], v);
      }
      ss[r] = s; vv[r] = v;
    }

#pragma unroll
    for (int r = 0; r < 4; ++r) { ss[r] += dppf<0xB1>(ss[r]);  vv[r] += dppf<0xB1>(vv[r]); }
#pragma unroll
    for (int r = 0; r < 4; ++r) { ss[r] += dppf<0x4E>(ss[r]);  vv[r] += dppf<0x4E>(vv[r]); }
#pragma unroll
    for (int r = 0; r < 4; ++r) { ss[r] += dppf<0x141>(ss[r]); vv[r] += dppf<0x141>(vv[r]); }
#pragma unroll
    for (int r = 0; r < 4; ++r) { ss[r] += dppf<0x140>(ss[r]); vv[r] += dppf<0x140>(vv[r]); }

    if (l16 == 0) {
#pragma unroll
      for (int r = 0; r < 4; ++r) {
        const float lm = M[r] + flog2(ss[r]);   // ss >= 1 -> log2 safe
        const float u  = vv[r] * frcp(ss[r]);
        const int p = sg * 16 + quad * 4 + r;
        trb[p * 64 + wstrip] = make_float2(lm, u);
      }
    }

    // rotate: convert prefetched A floats for next sg (short VALU tail;
    // the loads themselves were issued at loop top, latency already hidden)
    cvt8(nf0, nf1, ah0, al0);
    cvt8(nf2, nf3, ah1, al1);
    tq = ntq;
  }
}

// ==================== Phase 2: cross-strip merge (separate, parallel) =======
// R18-proven: one 64-lane wave per (b,p) row, 2048-wave parallelism. (R17's
// fused last-block merge was a 78us serial tail at 1.5% occupancy — never
// fuse this.)
__global__ __launch_bounds__(256) void k_merge(const float2* __restrict__ ws,
                                               float* __restrict__ out) {
  const int gt   = blockIdx.x * 256 + threadIdx.x;
  const int bp   = gt >> 6;
  const int lane = gt & 63;
  const float2 e = ws[(size_t)bp * 64 + lane];
  float M = e.x;
#pragma unroll
  for (int off = 32; off; off >>= 1) M = fmaxf(M, __shfl_xor(M, off, 64));
  const float f = fexp2(e.x - M);
  float S = f, V = f * e.y;
#pragma unroll
  for (int off = 32; off; off >>= 1) {
    S += __shfl_xor(S, off, 64);
    V += __shfl_xor(V, off, 64);
  }
  if (lane == 0) out[bp] = V / S;
}

// ============== Fallback (tiny ws): fused R1 structure + merge ==============
__global__ __launch_bounds__(256) void k_scan_fused(const float* __restrict__ data,
                                                    const float* __restrict__ targets,
                                                    const float* __restrict__ task_pool,
                                                    float2* __restrict__ ws) {
  const int b     = blockIdx.x >> 4;
  const int wid   = threadIdx.x >> 6;
  const int lane  = threadIdx.x & 63;
  const int chunk = ((blockIdx.x & 15) << 2) | wid;
  const int t     = (chunk << 6) | lane;
  float w[Dd];
#pragma unroll
  for (int d = 0; d < Dd; d += 4) {
    const float4 r = *(const float4*)(task_pool + (size_t)t * Dd + d);
    w[d] = r.x; w[d + 1] = r.y; w[d + 2] = r.z; w[d + 3] = r.w;
  }
  const float* drow = data + (size_t)b * (Pp * Dd);
  const float* tgt  = targets + b * Pp;
  float2* wsb       = ws + (size_t)b * (Pp * 64);
  float c = 0.f;
  for (int p = 0; p < Pp; ++p) {
    float a0 = 0.f, a1 = 0.f, a2 = 0.f, a3 = 0.f;
    const float* r = drow + p * Dd;
#pragma unroll
    for (int d = 0; d < Dd; d += 4) {
      a0 = fmaf(r[d], w[d], a0);         a1 = fmaf(r[d + 1], w[d + 1], a1);
      a2 = fmaf(r[d + 2], w[d + 2], a2); a3 = fmaf(r[d + 3], w[d + 3], a3);
    }
    const float pred = (a0 + a1) + (a2 + a3);
    float m = c;
#pragma unroll
    for (int off = 32; off; off >>= 1) m = fmaxf(m, __shfl_xor(m, off, 64));
    const float e = fexp2(c - m);
    float s = e, v = e * pred;
#pragma unroll
    for (int off = 32; off; off >>= 1) {
      s += __shfl_xor(s, off, 64);
      v += __shfl_xor(v, off, 64);
    }
    if (lane == 0) wsb[p * 64 + chunk] = make_float2(m + flog2(s), v * frcp(s));
    const float err = tgt[p] - pred;
    c = fmaf(C2 * err, err, c);
  }
}

extern "C" void kernel_launch(void* const* d_in, const int* in_sizes, int n_in,
                              void* d_out, int out_size, void* d_ws, size_t ws_size,
                              hipStream_t stream) {
  const float* data      = (const float*)d_in[0];
  const float* targets   = (const float*)d_in[1];
  const float* task_pool = (const float*)d_in[2];
  float* out = (float*)d_out;

  float2* trips = (float2*)d_ws;   // 4.2 MB
  if (ws_size >= WS_NEED) {
    k_main <<<dim3(Bb * 16), dim3(256), 0, stream>>>(data, targets, task_pool, trips);
    k_merge<<<dim3((Bb * Pp * 64) / 256), dim3(256), 0, stream>>>(trips, out);
  } else {
    k_scan_fused<<<dim3(512), dim3(256), 0, stream>>>(data, targets, task_pool, trips);
    k_merge<<<dim3((Bb * Pp * 64) / 256), dim3(256), 0, stream>>>(trips, out);
  }
}